// Round 1
// baseline (321.661 us; speedup 1.0000x reference)
//
#include <hip/hip_runtime.h>
#include <stdint.h>

typedef unsigned short ushort_t;
typedef __attribute__((ext_vector_type(8))) short bf16x8;   // 8 bf16 = 4 VGPRs (MFMA A/B frag)
typedef __attribute__((ext_vector_type(4))) float f32x4;    // MFMA C/D frag / fp32 vec-load

#define BM 256
#define BN 256
#define BK 64
#define SCALING 2.0f

static __device__ __forceinline__ unsigned short f2b(float f) {
    union { float f; unsigned int i; } v;
    v.f = f;
    unsigned int r = 0x7FFFu + ((v.i >> 16) & 1u);   // round-to-nearest-even
    return (unsigned short)((v.i + r) >> 16);
}

// async global->LDS, 16 bytes/lane. HW dest = wave-uniform base + lane*16.
static __device__ __forceinline__ void ld_g2l16(const void* g, void* l) {
    __builtin_amdgcn_global_load_lds(
        (const __attribute__((address_space(1))) void*)g,
        (__attribute__((address_space(3))) void*)l,
        16, 0, 0);
}

#define WAIT_VM8()   asm volatile("s_waitcnt vmcnt(8)" ::: "memory")
#define WAIT_VM0()   asm volatile("s_waitcnt vmcnt(0)" ::: "memory")
#define WAIT_LGKM0() asm volatile("s_waitcnt lgkmcnt(0)" ::: "memory")
#define SFENCE()     __builtin_amdgcn_sched_barrier(0)
#define BARRIER()    do { SFENCE(); __builtin_amdgcn_s_barrier(); SFENCE(); } while (0)

// ---------------------------------------------------------------------------
// Kernel 1: W_eff[o][d] = W[o][d] + SCALING * sum_r B[o][r]*A[r][d]  (fp32 in, bf16 out RNE)
// ---------------------------------------------------------------------------
__global__ void weff_kernel(const float* __restrict__ W,
                            const float* __restrict__ A,
                            const float* __restrict__ Bm,
                            ushort_t* __restrict__ Weff,
                            int D, int R) {
    int gid = blockIdx.x * blockDim.x + threadIdx.x;
    int perRow = D >> 3;
    if (gid >= D * perRow) return;
    int o  = gid / perRow;
    int d0 = (gid - o * perRow) << 3;

    float br[16];
    for (int r = 0; r < R; ++r) br[r] = SCALING * Bm[(size_t)o * R + r];

    float acc[8];
    #pragma unroll
    for (int j = 0; j < 8; ++j) acc[j] = W[(size_t)o * D + d0 + j];
    for (int r = 0; r < R; ++r) {
        #pragma unroll
        for (int j = 0; j < 8; ++j) acc[j] += br[r] * A[(size_t)r * D + d0 + j];
    }
    union { bf16x8 v; unsigned short s[8]; } ov;
    #pragma unroll
    for (int j = 0; j < 8; ++j) ov.s[j] = f2b(acc[j]);
    *(bf16x8*)(Weff + (size_t)o * D + d0) = ov.v;
}

// ---------------------------------------------------------------------------
// Kernel 2: x fp32 -> bf16 RNE (8 elems/thread)
// ---------------------------------------------------------------------------
__global__ void cvt_x_kernel(const float* __restrict__ x, ushort_t* __restrict__ xb, long n) {
    long gid = (long)(blockIdx.x * blockDim.x + threadIdx.x) * 8;
    if (gid >= n) return;
    f32x4 a = *(const f32x4*)(x + gid);
    f32x4 b = *(const f32x4*)(x + gid + 4);
    union { bf16x8 v; unsigned short s[8]; } ov;
    ov.s[0] = f2b(a[0]); ov.s[1] = f2b(a[1]); ov.s[2] = f2b(a[2]); ov.s[3] = f2b(a[3]);
    ov.s[4] = f2b(b[0]); ov.s[5] = f2b(b[1]); ov.s[6] = f2b(b[2]); ov.s[7] = f2b(b[3]);
    *(bf16x8*)(xb + gid) = ov.v;
}

// ---------------------------------------------------------------------------
// Kernel 3: Y[m][n] = sum_k X[m][k]*Wt[n][k] + bias[n]  (bf16 X/Wt, fp32 bias/out)
//   256x256 tile, BK=64, 8 waves (2M x 4N, 128x64 per wave), double-buffered
//   128 KiB LDS, prefetch depth 2 K-tiles, counted vmcnt(8) (never drains to 0
//   in steady state), XOR-swizzled LDS chunks (slot = chunk ^ (row&7); note
//   row&7 == lane&7 for all fragments so the read-side XOR is lane-constant),
//   setprio(1) around each 32-MFMA cluster, XCD-aware block remap.
//
//   Per-iteration schedule (tile t in buf[t&1]):
//     ds_read all 24 b128 (ks0 first)            -- compiler counts lgkmcnt
//     32 MFMA ks0                                -- overlaps trailing ds_reads
//     lgkmcnt(0); barrier                        -- buf[t&1] consumed by ALL waves
//     stage tile t+2 -> buf[t&1]  (8 g2l loads)  -- issue only, stays in flight
//     32 MFMA ks1                                -- hides load issue + latency
//     vmcnt(8); barrier                          -- tile t+1 landed; t+2 pending
// ---------------------------------------------------------------------------
__device__ __forceinline__ void stage_tile(const ushort_t* __restrict__ gA,
                                           const ushort_t* __restrict__ gB,
                                           ushort_t* lA, ushort_t* lB,
                                           size_t kOff, int K) {
    #pragma unroll
    for (int q = 0; q < 4; ++q) {
        ld_g2l16(gA + kOff + (size_t)(q * 64) * K, lA + q * 4096);
        ld_g2l16(gB + kOff + (size_t)(q * 64) * K, lB + q * 4096);
    }
}

__global__ __launch_bounds__(512, 2) void gemm_bt_bias(
    const ushort_t* __restrict__ X,     // [M,K] bf16
    const ushort_t* __restrict__ Wt,    // [N,K] bf16
    const float*    __restrict__ bias,  // [N]   fp32
    float*          __restrict__ Y,     // [M,N] fp32
    int M, int N, int K)
{
    __shared__ __align__(16) ushort_t sA[2][BM * BK];   // 2 x 32 KB
    __shared__ __align__(16) ushort_t sB[2][BN * BK];   // 2 x 32 KB

    const int tid  = threadIdx.x;
    const int lane = tid & 63;
    const int wave = tid >> 6;
    const int wm   = wave >> 2;          // 0..1  -> rows [wm*128, +128)
    const int wn   = wave & 3;           // 0..3  -> cols [wn*64,  +64)

    // ---- XCD-aware tile assignment ----
    const int nT = N / BN;
    const int mT = M / BM;
    int mTile, nTile;
    if (((mT * nT) & 7) == 0 && (((mT * nT) >> 3) % nT) == 0) {
        const int xcd = blockIdx.x & 7;
        const int loc = blockIdx.x >> 3;
        const int mPerXcd = ((mT * nT) >> 3) / nT;
        mTile = xcd * mPerXcd + loc / nT;
        nTile = loc % nT;
    } else {
        nTile = blockIdx.x % nT;
        mTile = blockIdx.x / nT;
    }
    const int mBase = mTile * BM;
    const int nBase = nTile * BN;

    // ---- staging: thread tid writes LDS bytes [tid*16 + q*8192); that cell is
    //      (row = tid>>3 + q*64, slot = tid&7); slot s of row r holds chunk s^(r&7)
    const int sRow   = tid >> 3;
    const int sChunk = (tid & 7) ^ (sRow & 7);           // row&7 invariant under +64
    const ushort_t* gA = X  + (size_t)(mBase + sRow) * K + sChunk * 8;
    const ushort_t* gB = Wt + (size_t)(nBase + sRow) * K + sChunk * 8;
    ushort_t* lA = &sA[0][0] + tid * 8;
    ushort_t* lB = &sB[0][0] + tid * 8;

    // ---- fragment read addressing (row&7 == lane&7 for every fragment row) ----
    const int fRow  = lane & 15;
    const int g     = lane >> 4;
    const int aBase = (wm * 128 + fRow) * BK;            // ushort index
    const int bBase = (wn * 64  + fRow) * BK;
    const int s0    = ((0 + g) ^ (lane & 7)) * 8;        // kstep 0 slot offset
    const int s1    = ((4 + g) ^ (lane & 7)) * 8;        // kstep 1 slot offset

    f32x4 acc[8][4];
    #pragma unroll
    for (int i = 0; i < 8; ++i)
        #pragma unroll
        for (int j = 0; j < 4; ++j)
            acc[i][j] = (f32x4){0.f, 0.f, 0.f, 0.f};

    const int nt = K / BK;

    // ---- prologue: stage tiles 0 and 1; wait only for tile 0 (8 loads in flight)
    stage_tile(gA, gB, lA,           lB,           0,  K);
    stage_tile(gA, gB, lA + BM * BK, lB + BN * BK, BK, K);
    WAIT_VM8();
    BARRIER();

    for (int t = 0; t < nt; ++t) {
        const ushort_t* pA = &sA[t & 1][0];
        const ushort_t* pB = &sB[t & 1][0];

        bf16x8 aF0[8], aF1[8], bF0[4], bF1[4];
        #pragma unroll
        for (int i = 0; i < 8; ++i) aF0[i] = *(const bf16x8*)(pA + aBase + i * (16 * BK) + s0);
        #pragma unroll
        for (int j = 0; j < 4; ++j) bF0[j] = *(const bf16x8*)(pB + bBase + j * (16 * BK) + s0);
        #pragma unroll
        for (int i = 0; i < 8; ++i) aF1[i] = *(const bf16x8*)(pA + aBase + i * (16 * BK) + s1);
        #pragma unroll
        for (int j = 0; j < 4; ++j) bF1[j] = *(const bf16x8*)(pB + bBase + j * (16 * BK) + s1);

        __builtin_amdgcn_s_setprio(1);
        #pragma unroll
        for (int i = 0; i < 8; ++i)
            #pragma unroll
            for (int j = 0; j < 4; ++j)
                acc[i][j] = __builtin_amdgcn_mfma_f32_16x16x32_bf16(aF0[i], bF0[j], acc[i][j], 0, 0, 0);
        __builtin_amdgcn_s_setprio(0);

        WAIT_LGKM0();          // all 24 ds_reads of buf[t&1] complete (this wave)
        BARRIER();             // ... and for every wave -> buf[t&1] free to overwrite

        if (t + 2 < nt) {
            stage_tile(gA, gB,
                       lA + (t & 1) * (BM * BK),
                       lB + (t & 1) * (BN * BK),
                       (size_t)(t + 2) * BK, K);
        }

        __builtin_amdgcn_s_setprio(1);
        #pragma unroll
        for (int i = 0; i < 8; ++i)
            #pragma unroll
            for (int j = 0; j < 4; ++j)
                acc[i][j] = __builtin_amdgcn_mfma_f32_16x16x32_bf16(aF1[i], bF1[j], acc[i][j], 0, 0, 0);
        __builtin_amdgcn_s_setprio(0);

        if (t + 2 < nt)      { WAIT_VM8(); }   // tile t+1 landed; t+2's 8 loads stay in flight
        else if (t + 1 < nt) { WAIT_VM0(); }   // tail: drain so last tile is visible
        BARRIER();
    }

    // ---- epilogue: C/D layout col(n)=lane&15, row(m)=(lane>>4)*4+reg ----
    const int col  = lane & 15;
    const int rowq = (lane >> 4) * 4;
    #pragma unroll
    for (int j = 0; j < 4; ++j) {
        const int n    = nBase + wn * 64 + j * 16 + col;
        const float bv = bias[n];
        #pragma unroll
        for (int i = 0; i < 8; ++i) {
            const int mRow = mBase + wm * 128 + i * 16 + rowq;
            #pragma unroll
            for (int r = 0; r < 4; ++r)
                Y[(size_t)(mRow + r) * N + n] = acc[i][j][r] + bv;
        }
    }
}

// ---------------------------------------------------------------------------
// Fallback (only if ws too small / shapes odd): correct fused fp32 kernel.
// ---------------------------------------------------------------------------
__global__ __launch_bounds__(256) void fused_naive(
    const float* __restrict__ x, const float* __restrict__ W,
    const float* __restrict__ b, const float* __restrict__ A,
    const float* __restrict__ Bm, float* __restrict__ y, int D, int R)
{
    extern __shared__ float smem[];
    float* sx  = smem;
    float* red = smem + D;
    float* sh  = red + 256;
    const int tid = threadIdx.x;
    const int m   = blockIdx.x;

    for (int i = tid; i < D; i += 256) sx[i] = x[(size_t)m * D + i];
    __syncthreads();

    for (int r = 0; r < R; ++r) {
        float p = 0.f;
        for (int k = tid; k < D; k += 256) p += sx[k] * A[(size_t)r * D + k];
        red[tid] = p; __syncthreads();
        for (int s = 128; s > 0; s >>= 1) {
            if (tid < s) red[tid] += red[tid + s];
            __syncthreads();
        }
        if (tid == 0) sh[r] = red[0];
        __syncthreads();
    }

    for (int n = tid; n < D; n += 256) {
        float base = 0.f;
        const float* wr = W + (size_t)n * D;
        for (int k = 0; k < D; ++k) base += sx[k] * wr[k];
        float lora = 0.f;
        for (int r = 0; r < R; ++r) lora += sh[r] * Bm[(size_t)n * R + r];
        y[(size_t)m * D + n] = base + b[n] + SCALING * lora;
    }
}

extern "C" void kernel_launch(void* const* d_in, const int* in_sizes, int n_in,
                              void* d_out, int out_size, void* d_ws, size_t ws_size,
                              hipStream_t stream) {
    const float* x  = (const float*)d_in[0];
    const float* W  = (const float*)d_in[1];
    const float* b  = (const float*)d_in[2];
    const float* A  = (const float*)d_in[3];
    const float* Bm = (const float*)d_in[4];
    float* y = (float*)d_out;

    const int D = in_sizes[2];                 // 1024
    const int R = in_sizes[3] / D;             // 8
    const int M = in_sizes[0] / D;             // 32768
    const long xN = (long)M * D;

    const size_t weffBytes = (size_t)D * D * sizeof(ushort_t);   // 2 MB
    const size_t xbBytes   = (size_t)xN * sizeof(ushort_t);      // 67 MB

    if (ws_size >= weffBytes + xbBytes &&
        (D % BN) == 0 && (M % BM) == 0 && (D % BK) == 0 && D >= 2 * BK) {
        ushort_t* Weff = (ushort_t*)d_ws;
        ushort_t* xb   = (ushort_t*)((char*)d_ws + weffBytes);

        int wthreads = D * (D / 8);
        weff_kernel<<<dim3((wthreads + 255) / 256), 256, 0, stream>>>(W, A, Bm, Weff, D, R);

        long cthreads = xN / 8;
        cvt_x_kernel<<<dim3((unsigned)((cthreads + 255) / 256)), 256, 0, stream>>>(x, xb, xN);

        dim3 grid((M / BM) * (D / BN));        // 1D; kernel does XCD-aware remap
        gemm_bt_bias<<<grid, 512, 0, stream>>>(xb, Weff, b, y, M, D, D);
    } else {
        size_t shmem = (size_t)(D + 256 + R) * sizeof(float);
        fused_naive<<<dim3(M), 256, shmem, stream>>>(x, W, b, A, Bm, y, D, R);
    }
}